// Round 5
// baseline (1494.217 us; speedup 1.0000x reference)
//
#include <hip/hip_runtime.h>
#include <hip/hip_bf16.h>

typedef __attribute__((ext_vector_type(4))) float f32x4;
typedef __attribute__((ext_vector_type(8))) short short8;
typedef __attribute__((ext_vector_type(8))) __bf16 bf16x8;

union FragU { bf16x8 h; short8 s; };

// ---------------------------------------------------------------------------
// Layer-0 GEMM + cache production.
//   P[split][M][64]  = A_f32[M][K] @ BT[64][Kpad]^T      (MFMA, bf16 inputs)
//   Ac (bf16 cache)  = A converted, laid out in MFMA fragment order:
//     Ac[rowBlk][kt][(w*4+ks*2+m)*64 + lane] : 8 bf16 (16 B) per slot
//     (tile = 128 rows x 64 k = 8192 elems = 16 KB)
// No LDS, no barriers: per-lane f32 gathers -> cvt -> MFMA + coalesced store.
// ---------------------------------------------------------------------------
__global__ __launch_bounds__(256) void gemm_l0(
    const float* __restrict__ Au, const __bf16* __restrict__ BTu,
    __bf16* __restrict__ AcU, float* __restrict__ Pu,
    int Mu, int Ku, int KTu, int padKu,
    const float* __restrict__ Am, const __bf16* __restrict__ BTm,
    __bf16* __restrict__ AcM, float* __restrict__ Pm,
    int Mm, int Km, int KTm, int padKm,
    int nbU, int rbU, int rbM, int TC)
{
  const int t = threadIdx.x;
  const int w = t >> 6;
  const int lane = t & 63;
  const int r = lane & 15;
  const int g = lane >> 4;

  const float* A; const __bf16* BT; __bf16* Ac; float* P;
  int M, K, KT, Kpad, rowBlk, split;
  {
    int bx = blockIdx.x;
    if (bx < nbU) {
      A = Au; BT = BTu; Ac = AcU; P = Pu; M = Mu; K = Ku; KT = KTu; Kpad = padKu;
      rowBlk = bx % rbU; split = bx / rbU;
    } else {
      int b2 = bx - nbU;
      A = Am; BT = BTm; Ac = AcM; P = Pm; M = Mm; K = Km; KT = KTm; Kpad = padKm;
      rowBlk = b2 % rbM; split = b2 / rbM;
    }
  }
  const int rowBase = rowBlk * 128;
  const int tLo = split * TC;
  const int nt = min(TC, KT - tLo);

  f32x4 acc[2][4];
  #pragma unroll
  for (int m = 0; m < 2; ++m)
    #pragma unroll
    for (int n = 0; n < 4; ++n)
      acc[m][n] = (f32x4){0.f, 0.f, 0.f, 0.f};

  const float* rp[2];
  #pragma unroll
  for (int m = 0; m < 2; ++m) {
    int row = rowBase + w * 32 + m * 16 + r; if (row > M - 1) row = M - 1;
    rp[m] = A + (size_t)row * K;
  }
  const __bf16* bp[4];
  #pragma unroll
  for (int n = 0; n < 4; ++n)
    bp[n] = BT + (size_t)(n * 16 + r) * Kpad + g * 8;

  __bf16* cbase = Ac + ((size_t)rowBlk * KT) * 8192
                + ((w * 4) * 64 + lane) * 8;   // + kt*8192 + (ks*2+m)*512

  for (int h = 0; h < 2 * nt; ++h) {
    const int kt = tLo + (h >> 1);
    const int ks = h & 1;
    const int k0 = kt * 64 + ks * 32;
    const int kAbs = k0 + g * 8;
    const bool ok = kAbs < K;          // 8 | K -> granule all-in/out
    const int ka = ok ? kAbs : 0;

    FragU bF[4], aF[2];
    #pragma unroll
    for (int n = 0; n < 4; ++n)
      bF[n].s = *(const short8*)(bp[n] + k0);   // Kpad region zero-filled
    #pragma unroll
    for (int m = 0; m < 2; ++m) {
      f32x4 a0 = *(const f32x4*)(rp[m] + ka);
      f32x4 a1 = *(const f32x4*)(rp[m] + ka + 4);
      bf16x8 hh;
      hh[0] = (__bf16)a0[0]; hh[1] = (__bf16)a0[1];
      hh[2] = (__bf16)a0[2]; hh[3] = (__bf16)a0[3];
      hh[4] = (__bf16)a1[0]; hh[5] = (__bf16)a1[1];
      hh[6] = (__bf16)a1[2]; hh[7] = (__bf16)a1[3];
      aF[m].h = hh;
      if (!ok) aF[m].s = (short8){0,0,0,0,0,0,0,0};
    }
    #pragma unroll
    for (int m = 0; m < 2; ++m)
      #pragma unroll
      for (int n = 0; n < 4; ++n)
        acc[m][n] = __builtin_amdgcn_mfma_f32_16x16x32_bf16(
            aF[m].s, bF[n].s, acc[m][n], 0, 0, 0);
    // coalesced cache store: 64 lanes x 16 B contiguous per (ks,m) slot
    #pragma unroll
    for (int m = 0; m < 2; ++m)
      *(short8*)(cbase + (size_t)kt * 8192 + (ks * 2 + m) * 512) = aF[m].s;
  }

  // epilogue: C/D layout col = lane&15, row = (lane>>4)*4 + reg
  float* Pp = P + (size_t)split * M * 64;
  #pragma unroll
  for (int m = 0; m < 2; ++m) {
    #pragma unroll
    for (int j = 0; j < 4; ++j) {
      const int row = rowBase + w * 32 + m * 16 + g * 4 + j;
      if (row < M) {
        #pragma unroll
        for (int n = 0; n < 4; ++n)
          Pp[(size_t)row * 64 + n * 16 + r] = acc[m][n][j];
      }
    }
  }
}

// ---------------------------------------------------------------------------
// Layers 1-2 GEMM over fragment-ordered bf16 cache. No LDS, no barriers.
// A fragments: contiguous 1 KB per wave-instruction (perfect coalescing).
// B fragments: per-lane 16-B gathers, L1/L2 resident.
// ---------------------------------------------------------------------------
__global__ __launch_bounds__(256) void gemm_l12(
    const __bf16* __restrict__ AcU, const __bf16* __restrict__ BTu,
    float* __restrict__ Pu, int Mu, int KTu, int padKu,
    const __bf16* __restrict__ AcM, const __bf16* __restrict__ BTm,
    float* __restrict__ Pm, int Mm, int KTm, int padKm,
    int nbU, int rbU, int rbM, int TC)
{
  const int t = threadIdx.x;
  const int w = t >> 6;
  const int lane = t & 63;
  const int r = lane & 15;
  const int g = lane >> 4;

  const __bf16 *Ac, *BT; float* P;
  int M, KT, Kpad, rowBlk, split;
  {
    int bx = blockIdx.x;
    if (bx < nbU) {
      Ac = AcU; BT = BTu; P = Pu; M = Mu; KT = KTu; Kpad = padKu;
      rowBlk = bx % rbU; split = bx / rbU;
    } else {
      int b2 = bx - nbU;
      Ac = AcM; BT = BTm; P = Pm; M = Mm; KT = KTm; Kpad = padKm;
      rowBlk = b2 % rbM; split = b2 / rbM;
    }
  }
  const int rowBase = rowBlk * 128;
  const int tLo = split * TC;
  const int nt = min(TC, KT - tLo);

  f32x4 acc[2][4];
  #pragma unroll
  for (int m = 0; m < 2; ++m)
    #pragma unroll
    for (int n = 0; n < 4; ++n)
      acc[m][n] = (f32x4){0.f, 0.f, 0.f, 0.f};

  const __bf16* bp[4];
  #pragma unroll
  for (int n = 0; n < 4; ++n)
    bp[n] = BT + (size_t)(n * 16 + r) * Kpad + g * 8;

  const __bf16* abase = Ac + ((size_t)rowBlk * KT) * 8192
                      + ((w * 4) * 64 + lane) * 8;

  #pragma unroll 2
  for (int h = 0; h < 2 * nt; ++h) {
    const int kt = tLo + (h >> 1);
    const int ks = h & 1;
    const int k0 = kt * 64 + ks * 32;

    FragU bF[4], aF[2];
    #pragma unroll
    for (int m = 0; m < 2; ++m)
      aF[m].s = *(const short8*)(abase + (size_t)kt * 8192 + (ks * 2 + m) * 512);
    #pragma unroll
    for (int n = 0; n < 4; ++n)
      bF[n].s = *(const short8*)(bp[n] + k0);
    #pragma unroll
    for (int m = 0; m < 2; ++m)
      #pragma unroll
      for (int n = 0; n < 4; ++n)
        acc[m][n] = __builtin_amdgcn_mfma_f32_16x16x32_bf16(
            aF[m].s, bF[n].s, acc[m][n], 0, 0, 0);
  }

  float* Pp = P + (size_t)split * M * 64;
  #pragma unroll
  for (int m = 0; m < 2; ++m) {
    #pragma unroll
    for (int j = 0; j < 4; ++j) {
      const int row = rowBase + w * 32 + m * 16 + g * 4 + j;
      if (row < M) {
        #pragma unroll
        for (int n = 0; n < 4; ++n)
          Pp[(size_t)row * 64 + n * 16 + r] = acc[m][n][j];
      }
    }
  }
}

// ---------------------------------------------------------------------------
// Transpose + f32->bf16 convert with K padding:
//   in[K][64] f32 -> out[64][Kpad] bf16 (pad region zero-filled)
// ---------------------------------------------------------------------------
__global__ __launch_bounds__(256) void transpose_cvt(
    const float* __restrict__ in, __bf16* __restrict__ out, int K, int Kpad)
{
  __shared__ float tile[64][65];
  const int t = threadIdx.x;
  const int k0 = blockIdx.x * 64;
  #pragma unroll
  for (int i = 0; i < 4; ++i) {
    int f = t + i * 256;
    int k = f >> 4;
    int cc = (f & 15) << 2;
    if (k0 + k < K) {
      f32x4 v = *(const f32x4*)(in + (size_t)(k0 + k) * 64 + cc);
      tile[k][cc + 0] = v[0]; tile[k][cc + 1] = v[1];
      tile[k][cc + 2] = v[2]; tile[k][cc + 3] = v[3];
    }
  }
  __syncthreads();
  const int c = t >> 2;
  const int kc = (t & 3) << 4;
  #pragma unroll
  for (int h = 0; h < 2; ++h) {
    int kk = kc + h * 8;
    FragU p;
    if (k0 + kk < K) {           // 8-granules all-in/out (8 | K)
      #pragma unroll
      for (int j = 0; j < 8; ++j) p.h[j] = (__bf16)tile[kk + j][c];
    } else {
      p.s = (short8){0,0,0,0,0,0,0,0};
    }
    *(short8*)(out + (size_t)c * Kpad + k0 + kk) = p.s;
  }
}

// ---------------------------------------------------------------------------
// out[i][c] = LeakyReLU( (sum_s P[s][i][:] + self[i][:]) . W[c][:] + 2*b[c] )
// ---------------------------------------------------------------------------
__global__ __launch_bounds__(256) void layer_reduce(
    const float* __restrict__ P, int S,
    const float* __restrict__ self, const float* __restrict__ W,
    const float* __restrict__ b, float* __restrict__ out, int M)
{
  __shared__ float xs[4][64];
  const int t = threadIdx.x;
  const int c = t & 63;
  const int grp = t >> 6;
  const int row = blockIdx.x * 4 + grp;
  if (row < M) {
    float x = self[(size_t)row * 64 + c];
    for (int s = 0; s < S; ++s)
      x += P[(size_t)s * M * 64 + (size_t)row * 64 + c];
    xs[grp][c] = x;
  }
  __syncthreads();
  if (row >= M) return;
  float acc = 0.f;
  const f32x4* Wc = (const f32x4*)(W + c * 64);
  #pragma unroll
  for (int k4 = 0; k4 < 16; ++k4) {
    f32x4 wv = Wc[k4];
    acc += xs[grp][k4 * 4 + 0] * wv[0] + xs[grp][k4 * 4 + 1] * wv[1]
         + xs[grp][k4 * 4 + 2] * wv[2] + xs[grp][k4 * 4 + 3] * wv[3];
  }
  float v = acc + 2.0f * b[c];
  out[(size_t)row * 64 + c] = (v > 0.f) ? v : 0.01f * v;
}

// ---------------------------------------------------------------------------
__global__ __launch_bounds__(256) void gather_score(
    const int* __restrict__ uid, const int* __restrict__ mid,
    const float* __restrict__ u0, const float* __restrict__ u1,
    const float* __restrict__ u2, const float* __restrict__ u3,
    const float* __restrict__ m0, const float* __restrict__ m1,
    const float* __restrict__ m2, const float* __restrict__ m3,
    const float* __restrict__ oW, const float* __restrict__ ob,
    float* __restrict__ scores, int B)
{
  const int wave = threadIdx.x >> 6;
  const int lane = threadIdx.x & 63;
  const int b = blockIdx.x * 4 + wave;
  if (b >= B) return;
  const size_t ub = (size_t)uid[b] * 64 + lane;
  const size_t mb = (size_t)mid[b] * 64 + lane;
  float acc = u0[ub] * m0[mb] * oW[lane]
            + u1[ub] * m1[mb] * oW[64 + lane]
            + u2[ub] * m2[mb] * oW[128 + lane]
            + u3[ub] * m3[mb] * oW[192 + lane];
  #pragma unroll
  for (int off = 32; off > 0; off >>= 1)
    acc += __shfl_down(acc, off, 64);
  if (lane == 0) scores[b] = acc + ob[0];
}

// ---------------------------------------------------------------------------
extern "C" void kernel_launch(void* const* d_in, const int* in_sizes, int n_in,
                              void* d_out, int out_size, void* d_ws, size_t ws_size,
                              hipStream_t stream)
{
  const float* user_adj  = (const float*)d_in[0];
  const float* movie_adj = (const float*)d_in[1];
  const int*   user_id   = (const int*)d_in[2];
  const int*   movie_id  = (const int*)d_in[3];
  const float* user_emb  = (const float*)d_in[4];
  const float* movie_emb = (const float*)d_in[5];
  const float* user_Ws   = (const float*)d_in[6];
  const float* user_bs   = (const float*)d_in[7];
  const float* movie_Ws  = (const float*)d_in[8];
  const float* movie_bs  = (const float*)d_in[9];
  const float* out_W     = (const float*)d_in[10];
  const float* out_b     = (const float*)d_in[11];

  const int NU = 20000, NM = 10000, E = 64, B = 8192;
  const int rbU = 157, rbM = 79;          // ceil(M/128)
  const int KT_U = 157, KT_M = 313;       // ceil(K/64)
  const int NMpad = KT_U * 64;            // 10048
  const int NUpad = KT_M * 64;            // 20032
  const int SU = 4, SM = 8;               // k-splits
  const int TC = 40;                      // k-tiles per split (ceil for both)

  char* ws = (char*)d_ws;
  size_t o = 0;
  __bf16* Au_c = (__bf16*)(ws + o); o += (size_t)rbU * KT_U * 16384;  // 403.8 MB
  __bf16* Am_c = (__bf16*)(ws + o); o += (size_t)rbM * KT_M * 16384;  // 405.1 MB
  float*  uP   = (float*)(ws + o);  o += (size_t)SU * NU * 64 * 4;    //  20.5 MB
  float*  mP   = (float*)(ws + o);  o += (size_t)SM * NM * 64 * 4;    //  20.5 MB
  float*  u1   = (float*)(ws + o);  o += (size_t)NU * 64 * 4;
  float*  u2   = (float*)(ws + o);  o += (size_t)NU * 64 * 4;
  float*  m1   = (float*)(ws + o);  o += (size_t)NM * 64 * 4;
  float*  m2   = (float*)(ws + o);  o += (size_t)NM * 64 * 4;
  __bf16* uT   = (__bf16*)(ws + o); o += (size_t)64 * NUpad * 2;
  __bf16* mT   = (__bf16*)(ws + o); o += (size_t)64 * NMpad * 2;

  float* scores = (float*)d_out;
  float* u3 = scores + B;
  float* m3 = u3 + (size_t)NU * E;

  const int nbU = rbU * SU;   // 628
  const int nbM = rbM * SM;   // 632

  const float* uCur = user_emb;
  const float* mCur = movie_emb;
  for (int l = 0; l < 3; ++l) {
    float* uNext = (l == 0) ? u1 : (l == 1) ? u2 : u3;
    float* mNext = (l == 0) ? m1 : (l == 1) ? m2 : m3;

    transpose_cvt<<<NMpad / 64, 256, 0, stream>>>(mCur, mT, NM, NMpad);
    transpose_cvt<<<NUpad / 64, 256, 0, stream>>>(uCur, uT, NU, NUpad);

    if (l == 0) {
      gemm_l0<<<nbU + nbM, 256, 0, stream>>>(
          user_adj, mT, Au_c, uP, NU, NM, KT_U, NMpad,
          movie_adj, uT, Am_c, mP, NM, NU, KT_M, NUpad,
          nbU, rbU, rbM, TC);
    } else {
      gemm_l12<<<nbU + nbM, 256, 0, stream>>>(
          Au_c, mT, uP, NU, KT_U, NMpad,
          Am_c, uT, mP, NM, KT_M, NUpad,
          nbU, rbU, rbM, TC);
    }

    layer_reduce<<<(NU + 3) / 4, 256, 0, stream>>>(
        uP, SU, uCur, user_Ws + (size_t)l * E * E, user_bs + (size_t)l * E, uNext, NU);
    layer_reduce<<<(NM + 3) / 4, 256, 0, stream>>>(
        mP, SM, mCur, movie_Ws + (size_t)l * E * E, movie_bs + (size_t)l * E, mNext, NM);
    uCur = uNext; mCur = mNext;
  }
  gather_score<<<(B + 3) / 4, 256, 0, stream>>>(
      user_id, movie_id, user_emb, u1, u2, u3,
      movie_emb, m1, m2, m3, out_W, out_b, scores, B);
}

// Round 7
// 1351.061 us; speedup vs baseline: 1.1060x; 1.1060x over previous
//
#include <hip/hip_runtime.h>
#include <hip/hip_bf16.h>

typedef __attribute__((ext_vector_type(4))) float f32x4;
typedef __attribute__((ext_vector_type(8))) short short8;
typedef __attribute__((ext_vector_type(8))) __bf16 bf16x8;

union FragU { bf16x8 h; short8 s; };

static __device__ __forceinline__ short8 cvt8(const f32x4 a0, const f32x4 a1) {
  bf16x8 hv;
  hv[0] = (__bf16)a0[0]; hv[1] = (__bf16)a0[1];
  hv[2] = (__bf16)a0[2]; hv[3] = (__bf16)a0[3];
  hv[4] = (__bf16)a1[0]; hv[5] = (__bf16)a1[1];
  hv[6] = (__bf16)a1[2]; hv[7] = (__bf16)a1[3];
  FragU u; u.h = hv; return u.s;
}

// ---------------------------------------------------------------------------
// Layer-0 GEMM + fragment-cache production, register-pipelined depth 3.
//   P[split][M][64] = A_f32[M][K] @ BT[64][Kpad]^T  (MFMA bf16)
//   Ac[rowBlk][kt][(w*4+ks*2+m)*64+lane] : 16B slots, MFMA fragment order.
// No LDS, no barriers. Each step h = 32 k-elems; slot s reloaded for h+3.
// ---------------------------------------------------------------------------
__global__ __launch_bounds__(256) void gemm_l0(
    const float* __restrict__ Au, const __bf16* __restrict__ BTu,
    __bf16* __restrict__ AcU, float* __restrict__ Pu,
    int Mu, int Ku, int KTu, int padKu,
    const float* __restrict__ Am, const __bf16* __restrict__ BTm,
    __bf16* __restrict__ AcM, float* __restrict__ Pm,
    int Mm, int Km, int KTm, int padKm,
    int nbU, int rbU, int rbM, int TC)
{
  const int t = threadIdx.x;
  const int w = t >> 6;
  const int lane = t & 63;
  const int r = lane & 15;
  const int g = lane >> 4;

  const float* A; const __bf16* BT; __bf16* Ac; float* P;
  int M, K, KT, Kpad, rowBlk, split;
  {
    int bx = blockIdx.x;
    if (bx < nbU) {
      A = Au; BT = BTu; Ac = AcU; P = Pu; M = Mu; K = Ku; KT = KTu; Kpad = padKu;
      rowBlk = bx % rbU; split = bx / rbU;
    } else {
      int b2 = bx - nbU;
      A = Am; BT = BTm; Ac = AcM; P = Pm; M = Mm; K = Km; KT = KTm; Kpad = padKm;
      rowBlk = b2 % rbM; split = b2 / rbM;
    }
  }
  const int rowBase = rowBlk * 128;
  const int tLo = split * TC;
  const int nt = min(TC, KT - tLo);
  const int H = 2 * nt;                 // 32-k steps
  const int kBase = tLo * 64 + g * 8;   // this lane's absolute k at h=0

  f32x4 acc[2][4];
  #pragma unroll
  for (int m = 0; m < 2; ++m)
    #pragma unroll
    for (int n = 0; n < 4; ++n)
      acc[m][n] = (f32x4){0.f, 0.f, 0.f, 0.f};

  const float* rp[2];
  #pragma unroll
  for (int m = 0; m < 2; ++m) {
    int row = rowBase + w * 32 + m * 16 + r; if (row > M - 1) row = M - 1;
    rp[m] = A + (size_t)row * K;
  }
  const __bf16* bp[4];
  #pragma unroll
  for (int n = 0; n < 4; ++n)
    bp[n] = BT + (size_t)(n * 16 + r) * Kpad + tLo * 64 + g * 8;

  __bf16* cb = Ac + (size_t)rowBlk * KT * 8192 + ((w * 4) * 64 + lane) * 8;

  f32x4 aR[3][2][2];
  FragU bF[3][4];

  auto l0_load = [&](int s, int hh) {
    int ko = kBase + hh * 32;
    int ka = (ko < K) ? ko : 0;
    aR[s][0][0] = *(const f32x4*)(rp[0] + ka);
    aR[s][0][1] = *(const f32x4*)(rp[0] + ka + 4);
    aR[s][1][0] = *(const f32x4*)(rp[1] + ka);
    aR[s][1][1] = *(const f32x4*)(rp[1] + ka + 4);
    #pragma unroll
    for (int n = 0; n < 4; ++n)
      bF[s][n].s = *(const short8*)(bp[n] + hh * 32);
  };

  auto l0_cons = [&](int s, int hh) {
    const bool ok = (kBase + hh * 32) < K;
    const short8 z8 = {0, 0, 0, 0, 0, 0, 0, 0};
    FragU aF[2];
    aF[0].s = ok ? cvt8(aR[s][0][0], aR[s][0][1]) : z8;
    aF[1].s = ok ? cvt8(aR[s][1][0], aR[s][1][1]) : z8;
    #pragma unroll
    for (int m = 0; m < 2; ++m)
      #pragma unroll
      for (int n = 0; n < 4; ++n)
        acc[m][n] = __builtin_amdgcn_mfma_f32_16x16x32_bf16(
            aF[m].s, bF[s][n].s, acc[m][n], 0, 0, 0);
    const int kt = tLo + (hh >> 1);
    const int ks = hh & 1;
    *(short8*)(cb + ((size_t)kt << 13) + ((size_t)(ks * 2 + 0) << 9)) = aF[0].s;
    *(short8*)(cb + ((size_t)kt << 13) + ((size_t)(ks * 2 + 1) << 9)) = aF[1].s;
  };

  // prologue (H >= 3 guaranteed by split config)
  #pragma unroll
  for (int s = 0; s < 3; ++s)
    l0_load(s, s);

  int h = 0;
  for (; h + 3 <= H; h += 3) {
    #pragma unroll
    for (int s = 0; s < 3; ++s) {
      l0_cons(s, h + s);
      int hn = h + 3 + s; if (hn > H - 1) hn = H - 1;
      l0_load(s, hn);
    }
  }
  if (h < H)     l0_cons(0, h);
  if (h + 1 < H) l0_cons(1, h + 1);

  // epilogue: C/D layout col = lane&15, row = (lane>>4)*4 + reg
  float* Pp = P + (size_t)split * M * 64;
  #pragma unroll
  for (int m = 0; m < 2; ++m) {
    #pragma unroll
    for (int j = 0; j < 4; ++j) {
      const int row = rowBase + w * 32 + m * 16 + g * 4 + j;
      if (row < M) {
        #pragma unroll
        for (int n = 0; n < 4; ++n)
          Pp[(size_t)row * 64 + n * 16 + r] = acc[m][n][j];
      }
    }
  }
}

// ---------------------------------------------------------------------------
// Layers 1-2 GEMM over fragment-ordered bf16 cache, register-pipelined
// depth 4. No LDS, no barriers. A-frag loads are 1 KB/wave contiguous.
// ---------------------------------------------------------------------------
__global__ __launch_bounds__(256) void gemm_l12(
    const __bf16* __restrict__ AcU, const __bf16* __restrict__ BTu,
    float* __restrict__ Pu, int Mu, int KTu, int padKu,
    const __bf16* __restrict__ AcM, const __bf16* __restrict__ BTm,
    float* __restrict__ Pm, int Mm, int KTm, int padKm,
    int nbU, int rbU, int rbM, int TC)
{
  const int t = threadIdx.x;
  const int w = t >> 6;
  const int lane = t & 63;
  const int r = lane & 15;
  const int g = lane >> 4;

  const __bf16 *Ac, *BT; float* P;
  int M, KT, Kpad, rowBlk, split;
  {
    int bx = blockIdx.x;
    if (bx < nbU) {
      Ac = AcU; BT = BTu; P = Pu; M = Mu; KT = KTu; Kpad = padKu;
      rowBlk = bx % rbU; split = bx / rbU;
    } else {
      int b2 = bx - nbU;
      Ac = AcM; BT = BTm; P = Pm; M = Mm; KT = KTm; Kpad = padKm;
      rowBlk = b2 % rbM; split = b2 / rbM;
    }
  }
  const int rowBase = rowBlk * 128;
  const int tLo = split * TC;
  const int nt = min(TC, KT - tLo);
  const int H = 2 * nt;

  f32x4 acc[2][4];
  #pragma unroll
  for (int m = 0; m < 2; ++m)
    #pragma unroll
    for (int n = 0; n < 4; ++n)
      acc[m][n] = (f32x4){0.f, 0.f, 0.f, 0.f};

  const __bf16* bp[4];
  #pragma unroll
  for (int n = 0; n < 4; ++n)
    bp[n] = BT + (size_t)(n * 16 + r) * Kpad + tLo * 64 + g * 8;

  const __bf16* ab = Ac + (size_t)rowBlk * KT * 8192 + ((w * 4) * 64 + lane) * 8;

  FragU aP[4][2], bP[4][4];

  auto l12_load = [&](int s, int hh) {
    const __bf16* ap = ab + ((size_t)(tLo + (hh >> 1)) << 13)
                          + ((size_t)((hh & 1) * 2) << 9);
    aP[s][0].s = *(const short8*)(ap);
    aP[s][1].s = *(const short8*)(ap + 512);
    #pragma unroll
    for (int n = 0; n < 4; ++n)
      bP[s][n].s = *(const short8*)(bp[n] + hh * 32);
  };

  auto l12_cons = [&](int s) {
    #pragma unroll
    for (int m = 0; m < 2; ++m)
      #pragma unroll
      for (int n = 0; n < 4; ++n)
        acc[m][n] = __builtin_amdgcn_mfma_f32_16x16x32_bf16(
            aP[s][m].s, bP[s][n].s, acc[m][n], 0, 0, 0);
  };

  // prologue (H >= 4 guaranteed by split config)
  #pragma unroll
  for (int s = 0; s < 4; ++s)
    l12_load(s, s);

  int h = 0;
  for (; h + 4 <= H; h += 4) {
    #pragma unroll
    for (int s = 0; s < 4; ++s) {
      l12_cons(s);
      int hn = h + 4 + s; if (hn > H - 1) hn = H - 1;
      l12_load(s, hn);
    }
  }
  if (h < H)     l12_cons(0);
  if (h + 1 < H) l12_cons(1);
  if (h + 2 < H) l12_cons(2);

  float* Pp = P + (size_t)split * M * 64;
  #pragma unroll
  for (int m = 0; m < 2; ++m) {
    #pragma unroll
    for (int j = 0; j < 4; ++j) {
      const int row = rowBase + w * 32 + m * 16 + g * 4 + j;
      if (row < M) {
        #pragma unroll
        for (int n = 0; n < 4; ++n)
          Pp[(size_t)row * 64 + n * 16 + r] = acc[m][n][j];
      }
    }
  }
}

// ---------------------------------------------------------------------------
// Transpose + f32->bf16 convert with K padding:
//   in[K][64] f32 -> out[64][Kpad] bf16 (pad region zero-filled)
// ---------------------------------------------------------------------------
__global__ __launch_bounds__(256) void transpose_cvt(
    const float* __restrict__ in, __bf16* __restrict__ out, int K, int Kpad)
{
  __shared__ float tile[64][65];
  const int t = threadIdx.x;
  const int k0 = blockIdx.x * 64;
  #pragma unroll
  for (int i = 0; i < 4; ++i) {
    int f = t + i * 256;
    int k = f >> 4;
    int cc = (f & 15) << 2;
    if (k0 + k < K) {
      f32x4 v = *(const f32x4*)(in + (size_t)(k0 + k) * 64 + cc);
      tile[k][cc + 0] = v[0]; tile[k][cc + 1] = v[1];
      tile[k][cc + 2] = v[2]; tile[k][cc + 3] = v[3];
    }
  }
  __syncthreads();
  const int c = t >> 2;
  const int kc = (t & 3) << 4;
  #pragma unroll
  for (int h = 0; h < 2; ++h) {
    int kk = kc + h * 8;
    FragU p;
    if (k0 + kk < K) {
      #pragma unroll
      for (int j = 0; j < 8; ++j) p.h[j] = (__bf16)tile[kk + j][c];
    } else {
      p.s = (short8){0,0,0,0,0,0,0,0};
    }
    *(short8*)(out + (size_t)c * Kpad + k0 + kk) = p.s;
  }
}

// ---------------------------------------------------------------------------
// out[i][c] = LeakyReLU( (sum_s P[s][i][:] + self[i][:]) . W[c][:] + 2*b[c] )
// ---------------------------------------------------------------------------
__global__ __launch_bounds__(256) void layer_reduce(
    const float* __restrict__ P, int S,
    const float* __restrict__ self, const float* __restrict__ W,
    const float* __restrict__ b, float* __restrict__ out, int M)
{
  __shared__ float xs[4][64];
  const int t = threadIdx.x;
  const int c = t & 63;
  const int grp = t >> 6;
  const int row = blockIdx.x * 4 + grp;
  if (row < M) {
    float x = self[(size_t)row * 64 + c];
    for (int s = 0; s < S; ++s)
      x += P[(size_t)s * M * 64 + (size_t)row * 64 + c];
    xs[grp][c] = x;
  }
  __syncthreads();
  if (row >= M) return;
  float acc = 0.f;
  const f32x4* Wc = (const f32x4*)(W + c * 64);
  #pragma unroll
  for (int k4 = 0; k4 < 16; ++k4) {
    f32x4 wv = Wc[k4];
    acc += xs[grp][k4 * 4 + 0] * wv[0] + xs[grp][k4 * 4 + 1] * wv[1]
         + xs[grp][k4 * 4 + 2] * wv[2] + xs[grp][k4 * 4 + 3] * wv[3];
  }
  float v = acc + 2.0f * b[c];
  out[(size_t)row * 64 + c] = (v > 0.f) ? v : 0.01f * v;
}

// ---------------------------------------------------------------------------
__global__ __launch_bounds__(256) void gather_score(
    const int* __restrict__ uid, const int* __restrict__ mid,
    const float* __restrict__ u0, const float* __restrict__ u1,
    const float* __restrict__ u2, const float* __restrict__ u3,
    const float* __restrict__ m0, const float* __restrict__ m1,
    const float* __restrict__ m2, const float* __restrict__ m3,
    const float* __restrict__ oW, const float* __restrict__ ob,
    float* __restrict__ scores, int B)
{
  const int wave = threadIdx.x >> 6;
  const int lane = threadIdx.x & 63;
  const int b = blockIdx.x * 4 + wave;
  if (b >= B) return;
  const size_t ub = (size_t)uid[b] * 64 + lane;
  const size_t mb = (size_t)mid[b] * 64 + lane;
  float acc = u0[ub] * m0[mb] * oW[lane]
            + u1[ub] * m1[mb] * oW[64 + lane]
            + u2[ub] * m2[mb] * oW[128 + lane]
            + u3[ub] * m3[mb] * oW[192 + lane];
  #pragma unroll
  for (int off = 32; off > 0; off >>= 1)
    acc += __shfl_down(acc, off, 64);
  if (lane == 0) scores[b] = acc + ob[0];
}

// ---------------------------------------------------------------------------
extern "C" void kernel_launch(void* const* d_in, const int* in_sizes, int n_in,
                              void* d_out, int out_size, void* d_ws, size_t ws_size,
                              hipStream_t stream)
{
  const float* user_adj  = (const float*)d_in[0];
  const float* movie_adj = (const float*)d_in[1];
  const int*   user_id   = (const int*)d_in[2];
  const int*   movie_id  = (const int*)d_in[3];
  const float* user_emb  = (const float*)d_in[4];
  const float* movie_emb = (const float*)d_in[5];
  const float* user_Ws   = (const float*)d_in[6];
  const float* user_bs   = (const float*)d_in[7];
  const float* movie_Ws  = (const float*)d_in[8];
  const float* movie_bs  = (const float*)d_in[9];
  const float* out_W     = (const float*)d_in[10];
  const float* out_b     = (const float*)d_in[11];

  const int NU = 20000, NM = 10000, E = 64, B = 8192;
  const int rbU = 157, rbM = 79;          // ceil(M/128)
  const int KT_U = 157, KT_M = 313;       // ceil(K/64)
  const int NMpad = KT_U * 64;            // 10048
  const int NUpad = KT_M * 64;            // 20032
  const int SU = 5, SM = 10;              // k-splits
  const int TC = 32;                      // k-tiles per split (covers both)

  char* ws = (char*)d_ws;
  size_t o = 0;
  __bf16* Au_c = (__bf16*)(ws + o); o += (size_t)rbU * KT_U * 16384;  // 403.8 MB
  __bf16* Am_c = (__bf16*)(ws + o); o += (size_t)rbM * KT_M * 16384;  // 405.1 MB
  float*  uP   = (float*)(ws + o);  o += (size_t)SU * NU * 64 * 4;    //  25.6 MB
  float*  mP   = (float*)(ws + o);  o += (size_t)SM * NM * 64 * 4;    //  25.6 MB
  float*  u1   = (float*)(ws + o);  o += (size_t)NU * 64 * 4;
  float*  u2   = (float*)(ws + o);  o += (size_t)NU * 64 * 4;
  float*  m1   = (float*)(ws + o);  o += (size_t)NM * 64 * 4;
  float*  m2   = (float*)(ws + o);  o += (size_t)NM * 64 * 4;
  __bf16* uT   = (__bf16*)(ws + o); o += (size_t)64 * NUpad * 2;
  __bf16* mT   = (__bf16*)(ws + o); o += (size_t)64 * NMpad * 2;

  float* scores = (float*)d_out;
  float* u3 = scores + B;
  float* m3 = u3 + (size_t)NU * E;

  const int nbU = rbU * SU;   // 785
  const int nbM = rbM * SM;   // 790

  const float* uCur = user_emb;
  const float* mCur = movie_emb;
  for (int l = 0; l < 3; ++l) {
    float* uNext = (l == 0) ? u1 : (l == 1) ? u2 : u3;
    float* mNext = (l == 0) ? m1 : (l == 1) ? m2 : m3;

    transpose_cvt<<<NMpad / 64, 256, 0, stream>>>(mCur, mT, NM, NMpad);
    transpose_cvt<<<NUpad / 64, 256, 0, stream>>>(uCur, uT, NU, NUpad);

    if (l == 0) {
      gemm_l0<<<nbU + nbM, 256, 0, stream>>>(
          user_adj, mT, Au_c, uP, NU, NM, KT_U, NMpad,
          movie_adj, uT, Am_c, mP, NM, NU, KT_M, NUpad,
          nbU, rbU, rbM, TC);
    } else {
      gemm_l12<<<nbU + nbM, 256, 0, stream>>>(
          Au_c, mT, uP, NU, KT_U, NMpad,
          Am_c, uT, mP, NM, KT_M, NUpad,
          nbU, rbU, rbM, TC);
    }

    layer_reduce<<<(NU + 3) / 4, 256, 0, stream>>>(
        uP, SU, uCur, user_Ws + (size_t)l * E * E, user_bs + (size_t)l * E, uNext, NU);
    layer_reduce<<<(NM + 3) / 4, 256, 0, stream>>>(
        mP, SM, mCur, movie_Ws + (size_t)l * E * E, movie_bs + (size_t)l * E, mNext, NM);
    uCur = uNext; mCur = mNext;
  }
  gather_score<<<(B + 3) / 4, 256, 0, stream>>>(
      user_id, movie_id, user_emb, u1, u2, u3,
      movie_emb, m1, m2, m3, out_W, out_b, scores, B);
}

// Round 8
// 1160.265 us; speedup vs baseline: 1.2878x; 1.1644x over previous
//
#include <hip/hip_runtime.h>
#include <hip/hip_bf16.h>

typedef __attribute__((ext_vector_type(4))) float f32x4;
typedef __attribute__((ext_vector_type(8))) short short8;
typedef __attribute__((ext_vector_type(8))) __bf16 bf16x8;

union FragU { bf16x8 h; short8 s; };

typedef const __attribute__((address_space(1))) void gvoid_t;
typedef __attribute__((address_space(3))) void lvoid_t;

static __device__ __forceinline__ void gload16(const void* g, void* l) {
  // async global->LDS: per-lane global src, LDS dest = wave-uniform base + lane*16
  __builtin_amdgcn_global_load_lds((gvoid_t*)g, (lvoid_t*)l, 16, 0, 0);
}

static __device__ __forceinline__ short8 cvt8(const f32x4 a0, const f32x4 a1) {
  bf16x8 hv;
  hv[0] = (__bf16)a0[0]; hv[1] = (__bf16)a0[1];
  hv[2] = (__bf16)a0[2]; hv[3] = (__bf16)a0[3];
  hv[4] = (__bf16)a1[0]; hv[5] = (__bf16)a1[1];
  hv[6] = (__bf16)a1[2]; hv[7] = (__bf16)a1[3];
  FragU u; u.h = hv; return u.s;
}

// ---------------------------------------------------------------------------
// Layer-0 GEMM + bf16 fragment-cache production.
//   P[split][M][64] = A_f32[M][K] @ BT[64][Kpad]^T  (MFMA bf16)
//   Cache tile (128 rows x 64 k = 16 KB): slot = ks*8 + w*2 + m (ks-major,
//   1 KB slots of lane*16B) so a 32-k half-tile is 8 KB CONTIGUOUS.
// Quad-buffered global_load_lds staging (BK=32), counted vmcnt + raw barrier:
// stage t+3 while computing t; barrier waits only until tile t+1 is landed.
// Per-wave per-iter VMEM: 5 staging loads + 2 cache stores.
// ---------------------------------------------------------------------------
__global__ __launch_bounds__(256) void gemm_l0(
    const float* __restrict__ Au, const __bf16* __restrict__ BTu,
    __bf16* __restrict__ AcU, float* __restrict__ Pu,
    int Mu, int Ku, int KTu, int padKu,
    const float* __restrict__ Am, const __bf16* __restrict__ BTm,
    __bf16* __restrict__ AcM, float* __restrict__ Pm,
    int Mm, int Km, int KTm, int padKm,
    int nbU, int rbU, int rbM)
{
  __shared__ float  sA[4][4096];   // 4 x 16 KB  [row(128)][granule(8)x4f32] XOR-swz
  __shared__ __bf16 sB[4][2048];   // 4 x  4 KB  [row(64)][k(32)] row-major

  const int t = threadIdx.x;
  const int w = t >> 6;
  const int lane = t & 63;
  const int r = lane & 15;
  const int g = lane >> 4;

  const float* A; const __bf16* BT; __bf16* Ac; float* P;
  int M, K, KT, Kpad, rowBlk, split;
  {
    int bx = blockIdx.x;
    if (bx < nbU) {
      A = Au; BT = BTu; Ac = AcU; P = Pu; M = Mu; K = Ku; KT = KTu; Kpad = padKu;
      rowBlk = bx % rbU; split = bx / rbU;
    } else {
      int b2 = bx - nbU;
      A = Am; BT = BTm; Ac = AcM; P = Pm; M = Mm; K = Km; KT = KTm; Kpad = padKm;
      rowBlk = b2 % rbM; split = b2 / rbM;
    }
  }
  const int rowBase = rowBlk * 128;
  const int NS = Kpad >> 5;            // total 32-k steps
  const int s0 = split * 64;
  const int ns = min(64, NS - s0);     // steps this block (>= 50 by config)

  f32x4 acc[2][4];
  #pragma unroll
  for (int m = 0; m < 2; ++m)
    #pragma unroll
    for (int n = 0; n < 4; ++n)
      acc[m][n] = (f32x4){0.f, 0.f, 0.f, 0.f};

  // per-thread staging sources (hoisted; only +k per step)
  const float* aRowP[4];
  int aOff[4];
  #pragma unroll
  for (int i = 0; i < 4; ++i) {
    int idx = i * 256 + t;             // granule slot 0..1023
    int rr = idx >> 3;                 // local row 0..127
    int p  = idx & 7;                  // 16B granule within 128B row-span
    int rowg = rowBase + rr; if (rowg > M - 1) rowg = M - 1;
    aRowP[i] = A + (size_t)rowg * K;
    aOff[i] = (p ^ (rr & 7)) << 2;     // src pre-swizzle (granule = 4 f32)
  }
  const __bf16* bSrc = BT + (size_t)(w * 16 + (lane >> 2)) * Kpad + (lane & 3) * 8;

  auto stage = [&](int buf, int h) {
    const int kk = (s0 + h) * 32;
    #pragma unroll
    for (int i = 0; i < 4; ++i) {
      int ke = kk + aOff[i];
      if (ke > K - 4) ke = K - 4;      // clamp OOB (content zeroed at consume)
      gload16(aRowP[i] + ke, &sA[buf][i * 1024 + w * 256]);
    }
    gload16(bSrc + kk, &sB[buf][w * 512]);
  };

  auto cons = [&](int buf, int h) {
    const int k32 = s0 + h;
    const bool ok = (k32 * 32 + g * 8) < K;   // 8|K: granule-pair all in/out
    const short8 z8 = {0, 0, 0, 0, 0, 0, 0, 0};
    FragU aF[2], bF[4];
    #pragma unroll
    for (int m = 0; m < 2; ++m) {
      const float* rowp = &sA[buf][(w * 32 + m * 16 + r) * 32];
      f32x4 a0 = *(const f32x4*)(rowp + (((2 * g)     ^ (r & 7)) << 2));
      f32x4 a1 = *(const f32x4*)(rowp + (((2 * g + 1) ^ (r & 7)) << 2));
      aF[m].s = ok ? cvt8(a0, a1) : z8;
    }
    #pragma unroll
    for (int n = 0; n < 4; ++n)
      bF[n].s = *(const short8*)&sB[buf][(n * 16 + r) * 32 + g * 8];
    #pragma unroll
    for (int m = 0; m < 2; ++m)
      #pragma unroll
      for (int n = 0; n < 4; ++n)
        acc[m][n] = __builtin_amdgcn_mfma_f32_16x16x32_bf16(
            aF[m].s, bF[n].s, acc[m][n], 0, 0, 0);
    // cache store: contiguous 1 KB per wave per slot
    const int kt = k32 >> 1, ks = k32 & 1;
    __bf16* cp = Ac + (((size_t)rowBlk * KT + kt) << 13) + (size_t)lane * 8;
    *(short8*)(cp + (ks * 8 + w * 2 + 0) * 512) = aF[0].s;
    *(short8*)(cp + (ks * 8 + w * 2 + 1) * 512) = aF[1].s;
  };

  stage(0, 0); stage(1, 1); stage(2, 2);
  asm volatile("s_waitcnt vmcnt(10)" ::: "memory");   // tile 0 landed
  __builtin_amdgcn_s_barrier();
  asm volatile("" ::: "memory");

  for (int h = 0; h < ns; ++h) {
    if (h + 3 < ns) stage((h + 3) & 3, h + 3);
    cons(h & 3, h);
    // guarantee tile h+1 landed; keep tiles h+2, h+3 loads in flight
    asm volatile("s_waitcnt vmcnt(10)" ::: "memory");
    __builtin_amdgcn_s_barrier();
    asm volatile("" ::: "memory");
  }

  // epilogue: C/D layout col = lane&15, row = (lane>>4)*4 + reg
  float* Pp = P + (size_t)split * M * 64;
  #pragma unroll
  for (int m = 0; m < 2; ++m) {
    #pragma unroll
    for (int j = 0; j < 4; ++j) {
      const int row = rowBase + w * 32 + m * 16 + g * 4 + j;
      if (row < M) {
        #pragma unroll
        for (int n = 0; n < 4; ++n)
          Pp[(size_t)row * 64 + n * 16 + r] = acc[m][n][j];
      }
    }
  }
}

// ---------------------------------------------------------------------------
// Layers 1-2 GEMM over the fragment-ordered bf16 cache.
// A staging = LINEAR 8 KB half-tile copy (perfect streaming); quad-buffered
// counted-vmcnt pipeline; 3 staging loads/wave/iter, no in-loop stores.
// ---------------------------------------------------------------------------
__global__ __launch_bounds__(256) void gemm_l12(
    const __bf16* __restrict__ AcU, const __bf16* __restrict__ BTu,
    float* __restrict__ Pu, int Mu, int KTu, int padKu,
    const __bf16* __restrict__ AcM, const __bf16* __restrict__ BTm,
    float* __restrict__ Pm, int Mm, int KTm, int padKm,
    int nbU, int rbU, int rbM)
{
  __shared__ __bf16 sA[4][4096];   // 4 x 8 KB  [slot(8)=w*2+m][lane(64)][8]
  __shared__ __bf16 sB[4][2048];   // 4 x 4 KB  [row(64)][k(32)]

  const int t = threadIdx.x;
  const int w = t >> 6;
  const int lane = t & 63;
  const int r = lane & 15;
  const int g = lane >> 4;

  const __bf16 *Ac, *BT; float* P;
  int M, KT, Kpad, rowBlk, split;
  {
    int bx = blockIdx.x;
    if (bx < nbU) {
      Ac = AcU; BT = BTu; P = Pu; M = Mu; KT = KTu; Kpad = padKu;
      rowBlk = bx % rbU; split = bx / rbU;
    } else {
      int b2 = bx - nbU;
      Ac = AcM; BT = BTm; P = Pm; M = Mm; KT = KTm; Kpad = padKm;
      rowBlk = b2 % rbM; split = b2 / rbM;
    }
  }
  const int rowBase = rowBlk * 128;
  const int NS = Kpad >> 5;
  const int s0 = split * 64;
  const int ns = min(64, NS - s0);

  f32x4 acc[2][4];
  #pragma unroll
  for (int m = 0; m < 2; ++m)
    #pragma unroll
    for (int n = 0; n < 4; ++n)
      acc[m][n] = (f32x4){0.f, 0.f, 0.f, 0.f};

  const __bf16* aBase = Ac + (((size_t)rowBlk * KT) << 13)
                      + (size_t)(w * 2) * 512 + (size_t)lane * 8;
  const __bf16* bSrc = BT + (size_t)(w * 16 + (lane >> 2)) * Kpad + (lane & 3) * 8;

  auto stage = [&](int buf, int h) {
    const size_t ko = ((size_t)(s0 + h)) << 12;   // half-tile offset (elems)
    gload16(aBase + ko,       &sA[buf][(w * 2 + 0) * 512]);
    gload16(aBase + ko + 512, &sA[buf][(w * 2 + 1) * 512]);
    gload16(bSrc + (s0 + h) * 32, &sB[buf][w * 512]);
  };

  auto cons = [&](int buf) {
    FragU aF[2], bF[4];
    aF[0].s = *(const short8*)&sA[buf][(w * 2 + 0) * 512 + lane * 8];
    aF[1].s = *(const short8*)&sA[buf][(w * 2 + 1) * 512 + lane * 8];
    #pragma unroll
    for (int n = 0; n < 4; ++n)
      bF[n].s = *(const short8*)&sB[buf][(n * 16 + r) * 32 + g * 8];
    #pragma unroll
    for (int m = 0; m < 2; ++m)
      #pragma unroll
      for (int n = 0; n < 4; ++n)
        acc[m][n] = __builtin_amdgcn_mfma_f32_16x16x32_bf16(
            aF[m].s, bF[n].s, acc[m][n], 0, 0, 0);
  };

  stage(0, 0); stage(1, 1); stage(2, 2);
  asm volatile("s_waitcnt vmcnt(6)" ::: "memory");    // tile 0 landed
  __builtin_amdgcn_s_barrier();
  asm volatile("" ::: "memory");

  for (int h = 0; h < ns; ++h) {
    if (h + 3 < ns) stage((h + 3) & 3, h + 3);
    cons(h & 3);
    asm volatile("s_waitcnt vmcnt(6)" ::: "memory");  // tile h+1 landed
    __builtin_amdgcn_s_barrier();
    asm volatile("" ::: "memory");
  }

  float* Pp = P + (size_t)split * M * 64;
  #pragma unroll
  for (int m = 0; m < 2; ++m) {
    #pragma unroll
    for (int j = 0; j < 4; ++j) {
      const int row = rowBase + w * 32 + m * 16 + g * 4 + j;
      if (row < M) {
        #pragma unroll
        for (int n = 0; n < 4; ++n)
          Pp[(size_t)row * 64 + n * 16 + r] = acc[m][n][j];
      }
    }
  }
}

// ---------------------------------------------------------------------------
// Transpose + f32->bf16 convert with K padding:
//   in[K][64] f32 -> out[64][Kpad] bf16 (pad region zero-filled)
// ---------------------------------------------------------------------------
__global__ __launch_bounds__(256) void transpose_cvt(
    const float* __restrict__ in, __bf16* __restrict__ out, int K, int Kpad)
{
  __shared__ float tile[64][65];
  const int t = threadIdx.x;
  const int k0 = blockIdx.x * 64;
  #pragma unroll
  for (int i = 0; i < 4; ++i) {
    int f = t + i * 256;
    int k = f >> 4;
    int cc = (f & 15) << 2;
    if (k0 + k < K) {
      f32x4 v = *(const f32x4*)(in + (size_t)(k0 + k) * 64 + cc);
      tile[k][cc + 0] = v[0]; tile[k][cc + 1] = v[1];
      tile[k][cc + 2] = v[2]; tile[k][cc + 3] = v[3];
    }
  }
  __syncthreads();
  const int c = t >> 2;
  const int kc = (t & 3) << 4;
  #pragma unroll
  for (int h = 0; h < 2; ++h) {
    int kk = kc + h * 8;
    FragU p;
    if (k0 + kk < K) {
      #pragma unroll
      for (int j = 0; j < 8; ++j) p.h[j] = (__bf16)tile[kk + j][c];
    } else {
      p.s = (short8){0,0,0,0,0,0,0,0};
    }
    *(short8*)(out + (size_t)c * Kpad + k0 + kk) = p.s;
  }
}

// ---------------------------------------------------------------------------
// out[i][c] = LeakyReLU( (sum_s P[s][i][:] + self[i][:]) . W[c][:] + 2*b[c] )
// ---------------------------------------------------------------------------
__global__ __launch_bounds__(256) void layer_reduce(
    const float* __restrict__ P, int S,
    const float* __restrict__ self, const float* __restrict__ W,
    const float* __restrict__ b, float* __restrict__ out, int M)
{
  __shared__ float xs[4][64];
  const int t = threadIdx.x;
  const int c = t & 63;
  const int grp = t >> 6;
  const int row = blockIdx.x * 4 + grp;
  if (row < M) {
    float x = self[(size_t)row * 64 + c];
    for (int s = 0; s < S; ++s)
      x += P[(size_t)s * M * 64 + (size_t)row * 64 + c];
    xs[grp][c] = x;
  }
  __syncthreads();
  if (row >= M) return;
  float acc = 0.f;
  const f32x4* Wc = (const f32x4*)(W + c * 64);
  #pragma unroll
  for (int k4 = 0; k4 < 16; ++k4) {
    f32x4 wv = Wc[k4];
    acc += xs[grp][k4 * 4 + 0] * wv[0] + xs[grp][k4 * 4 + 1] * wv[1]
         + xs[grp][k4 * 4 + 2] * wv[2] + xs[grp][k4 * 4 + 3] * wv[3];
  }
  float v = acc + 2.0f * b[c];
  out[(size_t)row * 64 + c] = (v > 0.f) ? v : 0.01f * v;
}

// ---------------------------------------------------------------------------
__global__ __launch_bounds__(256) void gather_score(
    const int* __restrict__ uid, const int* __restrict__ mid,
    const float* __restrict__ u0, const float* __restrict__ u1,
    const float* __restrict__ u2, const float* __restrict__ u3,
    const float* __restrict__ m0, const float* __restrict__ m1,
    const float* __restrict__ m2, const float* __restrict__ m3,
    const float* __restrict__ oW, const float* __restrict__ ob,
    float* __restrict__ scores, int B)
{
  const int wave = threadIdx.x >> 6;
  const int lane = threadIdx.x & 63;
  const int b = blockIdx.x * 4 + wave;
  if (b >= B) return;
  const size_t ub = (size_t)uid[b] * 64 + lane;
  const size_t mb = (size_t)mid[b] * 64 + lane;
  float acc = u0[ub] * m0[mb] * oW[lane]
            + u1[ub] * m1[mb] * oW[64 + lane]
            + u2[ub] * m2[mb] * oW[128 + lane]
            + u3[ub] * m3[mb] * oW[192 + lane];
  #pragma unroll
  for (int off = 32; off > 0; off >>= 1)
    acc += __shfl_down(acc, off, 64);
  if (lane == 0) scores[b] = acc + ob[0];
}

// ---------------------------------------------------------------------------
extern "C" void kernel_launch(void* const* d_in, const int* in_sizes, int n_in,
                              void* d_out, int out_size, void* d_ws, size_t ws_size,
                              hipStream_t stream)
{
  const float* user_adj  = (const float*)d_in[0];
  const float* movie_adj = (const float*)d_in[1];
  const int*   user_id   = (const int*)d_in[2];
  const int*   movie_id  = (const int*)d_in[3];
  const float* user_emb  = (const float*)d_in[4];
  const float* movie_emb = (const float*)d_in[5];
  const float* user_Ws   = (const float*)d_in[6];
  const float* user_bs   = (const float*)d_in[7];
  const float* movie_Ws  = (const float*)d_in[8];
  const float* movie_bs  = (const float*)d_in[9];
  const float* out_W     = (const float*)d_in[10];
  const float* out_b     = (const float*)d_in[11];

  const int NU = 20000, NM = 10000, E = 64, B = 8192;
  const int rbU = 157, rbM = 79;          // ceil(M/128)
  const int KT_U = 157, KT_M = 313;       // ceil(K/64)
  const int NMpad = KT_U * 64;            // 10048
  const int NUpad = KT_M * 64;            // 20032
  const int SU = 5, SM = 10;              // k-splits (64 32-k steps each)

  char* ws = (char*)d_ws;
  size_t o = 0;
  __bf16* Au_c = (__bf16*)(ws + o); o += (size_t)rbU * KT_U * 16384;  // 403.8 MB
  __bf16* Am_c = (__bf16*)(ws + o); o += (size_t)rbM * KT_M * 16384;  // 405.1 MB
  float*  uP   = (float*)(ws + o);  o += (size_t)SU * NU * 64 * 4;
  float*  mP   = (float*)(ws + o);  o += (size_t)SM * NM * 64 * 4;
  float*  u1   = (float*)(ws + o);  o += (size_t)NU * 64 * 4;
  float*  u2   = (float*)(ws + o);  o += (size_t)NU * 64 * 4;
  float*  m1   = (float*)(ws + o);  o += (size_t)NM * 64 * 4;
  float*  m2   = (float*)(ws + o);  o += (size_t)NM * 64 * 4;
  __bf16* uT   = (__bf16*)(ws + o); o += (size_t)64 * NUpad * 2;
  __bf16* mT   = (__bf16*)(ws + o); o += (size_t)64 * NMpad * 2;

  float* scores = (float*)d_out;
  float* u3 = scores + B;
  float* m3 = u3 + (size_t)NU * E;

  const int nbU = rbU * SU;   // 785
  const int nbM = rbM * SM;   // 790

  const float* uCur = user_emb;
  const float* mCur = movie_emb;
  for (int l = 0; l < 3; ++l) {
    float* uNext = (l == 0) ? u1 : (l == 1) ? u2 : u3;
    float* mNext = (l == 0) ? m1 : (l == 1) ? m2 : m3;

    transpose_cvt<<<NMpad / 64, 256, 0, stream>>>(mCur, mT, NM, NMpad);
    transpose_cvt<<<NUpad / 64, 256, 0, stream>>>(uCur, uT, NU, NUpad);

    if (l == 0) {
      gemm_l0<<<nbU + nbM, 256, 0, stream>>>(
          user_adj, mT, Au_c, uP, NU, NM, KT_U, NMpad,
          movie_adj, uT, Am_c, mP, NM, NU, KT_M, NUpad,
          nbU, rbU, rbM);
    } else {
      gemm_l12<<<nbU + nbM, 256, 0, stream>>>(
          Au_c, mT, uP, NU, KT_U, NMpad,
          Am_c, uT, mP, NM, KT_M, NUpad,
          nbU, rbU, rbM);
    }

    layer_reduce<<<(NU + 3) / 4, 256, 0, stream>>>(
        uP, SU, uCur, user_Ws + (size_t)l * E * E, user_bs + (size_t)l * E, uNext, NU);
    layer_reduce<<<(NM + 3) / 4, 256, 0, stream>>>(
        mP, SM, mCur, movie_Ws + (size_t)l * E * E, movie_bs + (size_t)l * E, mNext, NM);
    uCur = uNext; mCur = mNext;
  }
  gather_score<<<(B + 3) / 4, 256, 0, stream>>>(
      user_id, movie_id, user_emb, u1, u2, u3,
      movie_emb, m1, m2, m3, out_W, out_b, scores, B);
}

// Round 9
// 1160.084 us; speedup vs baseline: 1.2880x; 1.0002x over previous
//
#include <hip/hip_runtime.h>
#include <hip/hip_bf16.h>

typedef __attribute__((ext_vector_type(4))) float f32x4;
typedef __attribute__((ext_vector_type(8))) short short8;
typedef __attribute__((ext_vector_type(8))) __bf16 bf16x8;

union FragU { bf16x8 h; short8 s; };

typedef const __attribute__((address_space(1))) void gvoid_t;
typedef __attribute__((address_space(3))) void lvoid_t;

static __device__ __forceinline__ void gload16(const void* g, void* l) {
  // async global->LDS: per-lane global src, LDS dest = wave-uniform base + lane*16
  __builtin_amdgcn_global_load_lds((gvoid_t*)g, (lvoid_t*)l, 16, 0, 0);
}

static __device__ __forceinline__ short8 cvt8(const f32x4 a0, const f32x4 a1) {
  bf16x8 hv;
  hv[0] = (__bf16)a0[0]; hv[1] = (__bf16)a0[1];
  hv[2] = (__bf16)a0[2]; hv[3] = (__bf16)a0[3];
  hv[4] = (__bf16)a1[0]; hv[5] = (__bf16)a1[1];
  hv[6] = (__bf16)a1[2]; hv[7] = (__bf16)a1[3];
  FragU u; u.h = hv; return u.s;
}

// ---------------------------------------------------------------------------
// Layer-0 GEMM + bf16 fragment-cache production.
//   P[split][M][64] = A_f32[M][K] @ BT[64][Kpad]^T  (MFMA bf16)
// Quad-buffered global_load_lds staging (BK=32); loop = wait(h) -> barrier ->
// cons(h) -> stage(h+3, clamped). Exact vmcnt: 10/12/14 (5 loads + 2 cache
// stores per wave per iter; steady queue = [2S 5L 2S 5L 2S 5L] = 21, exclude
// tile-h loads -> 14). B staged with both-sides XOR swizzle (2-way, free);
// A staged with granule^row swizzle (2-way, free).
// ---------------------------------------------------------------------------
__global__ __launch_bounds__(256) void gemm_l0(
    const float* __restrict__ Au, const __bf16* __restrict__ BTu,
    __bf16* __restrict__ AcU, float* __restrict__ Pu,
    int Mu, int Ku, int KTu, int padKu,
    const float* __restrict__ Am, const __bf16* __restrict__ BTm,
    __bf16* __restrict__ AcM, float* __restrict__ Pm,
    int Mm, int Km, int KTm, int padKm,
    int nbU, int rbU, int rbM)
{
  __shared__ float  sA[4][4096];   // 4 x 16 KB  [row(128)][granule(8)] gran-XOR-swz
  __shared__ __bf16 sB[4][2048];   // 4 x  4 KB  [row(64)][gran(4)x8] gran-XOR-swz

  const int t = threadIdx.x;
  const int w = t >> 6;
  const int lane = t & 63;
  const int r = lane & 15;
  const int g = lane >> 4;

  const float* A; const __bf16* BT; __bf16* Ac; float* P;
  int M, K, KT, Kpad, rowBlk, split;
  {
    int bx = blockIdx.x;
    if (bx < nbU) {
      A = Au; BT = BTu; Ac = AcU; P = Pu; M = Mu; K = Ku; KT = KTu; Kpad = padKu;
      rowBlk = bx % rbU; split = bx / rbU;
    } else {
      int b2 = bx - nbU;
      A = Am; BT = BTm; Ac = AcM; P = Pm; M = Mm; K = Km; KT = KTm; Kpad = padKm;
      rowBlk = b2 % rbM; split = b2 / rbM;
    }
  }
  const int rowBase = rowBlk * 128;
  const int NS = Kpad >> 5;            // total 32-k steps
  const int s0 = split * 64;
  const int ns = min(64, NS - s0);     // steps this block (>= 50 by config)

  f32x4 acc[2][4];
  #pragma unroll
  for (int m = 0; m < 2; ++m)
    #pragma unroll
    for (int n = 0; n < 4; ++n)
      acc[m][n] = (f32x4){0.f, 0.f, 0.f, 0.f};

  // per-thread staging sources (hoisted; only +k per step)
  const float* aRowP[4];
  int aOff[4];
  #pragma unroll
  for (int i = 0; i < 4; ++i) {
    int idx = i * 256 + t;             // granule slot 0..1023
    int rr = idx >> 3;                 // local row 0..127
    int p  = idx & 7;                  // 16B granule within 128B row-span
    int rowg = rowBase + rr; if (rowg > M - 1) rowg = M - 1;
    aRowP[i] = A + (size_t)rowg * K;
    aOff[i] = (p ^ (rr & 7)) << 2;     // src pre-swizzle (granule = 4 f32)
  }
  // B: row = w*16 + (lane>>2); src granule = (lane&3) ^ ((row>>1)&3)
  const __bf16* bSrc = BT + (size_t)(w * 16 + (lane >> 2)) * Kpad
                     + (size_t)(((lane & 3) ^ ((lane >> 3) & 3)) * 8);

  auto stage = [&](int buf, int h) {
    const int kk = (s0 + h) * 32;
    #pragma unroll
    for (int i = 0; i < 4; ++i) {
      int ke = kk + aOff[i];
      if (ke > K - 4) ke = K - 4;      // clamp OOB (content zeroed at consume)
      gload16(aRowP[i] + ke, &sA[buf][i * 1024 + w * 256]);
    }
    gload16(bSrc + kk, &sB[buf][w * 512]);
  };

  auto cons = [&](int buf, int h) {
    const int k32 = s0 + h;
    const bool ok = (k32 * 32 + g * 8) < K;   // 8|K: granule-pair all in/out
    const short8 z8 = {0, 0, 0, 0, 0, 0, 0, 0};
    FragU aF[2], bF[4];
    #pragma unroll
    for (int m = 0; m < 2; ++m) {
      const float* rowp = &sA[buf][(w * 32 + m * 16 + r) * 32];
      f32x4 a0 = *(const f32x4*)(rowp + (((2 * g)     ^ (r & 7)) << 2));
      f32x4 a1 = *(const f32x4*)(rowp + (((2 * g + 1) ^ (r & 7)) << 2));
      aF[m].s = ok ? cvt8(a0, a1) : z8;
    }
    const int gb = g ^ ((r >> 1) & 3);        // read-side B swizzle
    #pragma unroll
    for (int n = 0; n < 4; ++n)
      bF[n].s = *(const short8*)&sB[buf][(n * 16 + r) * 32 + gb * 8];
    #pragma unroll
    for (int m = 0; m < 2; ++m)
      #pragma unroll
      for (int n = 0; n < 4; ++n)
        acc[m][n] = __builtin_amdgcn_mfma_f32_16x16x32_bf16(
            aF[m].s, bF[n].s, acc[m][n], 0, 0, 0);
    // cache store: contiguous 1 KB per wave per slot
    const int kt = k32 >> 1, ks = k32 & 1;
    __bf16* cp = Ac + (((size_t)rowBlk * KT + kt) << 13) + (size_t)lane * 8;
    *(short8*)(cp + (ks * 8 + w * 2 + 0) * 512) = aF[0].s;
    *(short8*)(cp + (ks * 8 + w * 2 + 1) * 512) = aF[1].s;
  };

  stage(0, 0); stage(1, 1); stage(2, 2);

  for (int h = 0; h < ns; ++h) {
    if (h == 0)      asm volatile("s_waitcnt vmcnt(10)" ::: "memory");
    else if (h == 1) asm volatile("s_waitcnt vmcnt(12)" ::: "memory");
    else             asm volatile("s_waitcnt vmcnt(14)" ::: "memory");
    __builtin_amdgcn_s_barrier();
    asm volatile("" ::: "memory");
    cons(h & 3, h);
    int hs = h + 3; if (hs > ns - 1) hs = ns - 1;   // clamp: keep queue full
    stage((h + 3) & 3, hs);
  }

  // epilogue: C/D layout col = lane&15, row = (lane>>4)*4 + reg
  float* Pp = P + (size_t)split * M * 64;
  #pragma unroll
  for (int m = 0; m < 2; ++m) {
    #pragma unroll
    for (int j = 0; j < 4; ++j) {
      const int row = rowBase + w * 32 + m * 16 + g * 4 + j;
      if (row < M) {
        #pragma unroll
        for (int n = 0; n < 4; ++n)
          Pp[(size_t)row * 64 + n * 16 + r] = acc[m][n][j];
      }
    }
  }
}

// ---------------------------------------------------------------------------
// Layers 1-2 GEMM over the fragment-ordered bf16 cache.
// A staging = LINEAR 8 KB half-tile copy; quad-buffered; 3 loads/wave/iter,
// exact vmcnt(6) (steady queue = [3L 3L 3L] = 9, exclude tile-h -> 6).
// ---------------------------------------------------------------------------
__global__ __launch_bounds__(256) void gemm_l12(
    const __bf16* __restrict__ AcU, const __bf16* __restrict__ BTu,
    float* __restrict__ Pu, int Mu, int KTu, int padKu,
    const __bf16* __restrict__ AcM, const __bf16* __restrict__ BTm,
    float* __restrict__ Pm, int Mm, int KTm, int padKm,
    int nbU, int rbU, int rbM)
{
  __shared__ __bf16 sA[4][4096];   // 4 x 8 KB  [slot(8)=w*2+m][lane(64)][8]
  __shared__ __bf16 sB[4][2048];   // 4 x 4 KB  [row(64)][gran(4)x8] gran-XOR-swz

  const int t = threadIdx.x;
  const int w = t >> 6;
  const int lane = t & 63;
  const int r = lane & 15;
  const int g = lane >> 4;

  const __bf16 *Ac, *BT; float* P;
  int M, KT, Kpad, rowBlk, split;
  {
    int bx = blockIdx.x;
    if (bx < nbU) {
      Ac = AcU; BT = BTu; P = Pu; M = Mu; KT = KTu; Kpad = padKu;
      rowBlk = bx % rbU; split = bx / rbU;
    } else {
      int b2 = bx - nbU;
      Ac = AcM; BT = BTm; P = Pm; M = Mm; KT = KTm; Kpad = padKm;
      rowBlk = b2 % rbM; split = b2 / rbM;
    }
  }
  const int rowBase = rowBlk * 128;
  const int NS = Kpad >> 5;
  const int s0 = split * 64;
  const int ns = min(64, NS - s0);

  f32x4 acc[2][4];
  #pragma unroll
  for (int m = 0; m < 2; ++m)
    #pragma unroll
    for (int n = 0; n < 4; ++n)
      acc[m][n] = (f32x4){0.f, 0.f, 0.f, 0.f};

  const __bf16* aBase = Ac + (((size_t)rowBlk * KT) << 13)
                      + (size_t)(w * 2) * 512 + (size_t)lane * 8;
  const __bf16* bSrc = BT + (size_t)(w * 16 + (lane >> 2)) * Kpad
                     + (size_t)(((lane & 3) ^ ((lane >> 3) & 3)) * 8);

  auto stage = [&](int buf, int h) {
    const size_t ko = ((size_t)(s0 + h)) << 12;   // half-tile offset (elems)
    gload16(aBase + ko,       &sA[buf][(w * 2 + 0) * 512]);
    gload16(aBase + ko + 512, &sA[buf][(w * 2 + 1) * 512]);
    gload16(bSrc + (s0 + h) * 32, &sB[buf][w * 512]);
  };

  auto cons = [&](int buf) {
    FragU aF[2], bF[4];
    aF[0].s = *(const short8*)&sA[buf][(w * 2 + 0) * 512 + lane * 8];
    aF[1].s = *(const short8*)&sA[buf][(w * 2 + 1) * 512 + lane * 8];
    const int gb = g ^ ((r >> 1) & 3);
    #pragma unroll
    for (int n = 0; n < 4; ++n)
      bF[n].s = *(const short8*)&sB[buf][(n * 16 + r) * 32 + gb * 8];
    #pragma unroll
    for (int m = 0; m < 2; ++m)
      #pragma unroll
      for (int n = 0; n < 4; ++n)
        acc[m][n] = __builtin_amdgcn_mfma_f32_16x16x32_bf16(
            aF[m].s, bF[n].s, acc[m][n], 0, 0, 0);
  };

  stage(0, 0); stage(1, 1); stage(2, 2);

  for (int h = 0; h < ns; ++h) {
    asm volatile("s_waitcnt vmcnt(6)" ::: "memory");  // tile h landed
    __builtin_amdgcn_s_barrier();
    asm volatile("" ::: "memory");
    cons(h & 3);
    int hs = h + 3; if (hs > ns - 1) hs = ns - 1;     // clamp: keep queue full
    stage((h + 3) & 3, hs);
  }

  float* Pp = P + (size_t)split * M * 64;
  #pragma unroll
  for (int m = 0; m < 2; ++m) {
    #pragma unroll
    for (int j = 0; j < 4; ++j) {
      const int row = rowBase + w * 32 + m * 16 + g * 4 + j;
      if (row < M) {
        #pragma unroll
        for (int n = 0; n < 4; ++n)
          Pp[(size_t)row * 64 + n * 16 + r] = acc[m][n][j];
      }
    }
  }
}

// ---------------------------------------------------------------------------
// Transpose + f32->bf16 convert with K padding:
//   in[K][64] f32 -> out[64][Kpad] bf16 (pad region zero-filled)
// ---------------------------------------------------------------------------
__global__ __launch_bounds__(256) void transpose_cvt(
    const float* __restrict__ in, __bf16* __restrict__ out, int K, int Kpad)
{
  __shared__ float tile[64][65];
  const int t = threadIdx.x;
  const int k0 = blockIdx.x * 64;
  #pragma unroll
  for (int i = 0; i < 4; ++i) {
    int f = t + i * 256;
    int k = f >> 4;
    int cc = (f & 15) << 2;
    if (k0 + k < K) {
      f32x4 v = *(const f32x4*)(in + (size_t)(k0 + k) * 64 + cc);
      tile[k][cc + 0] = v[0]; tile[k][cc + 1] = v[1];
      tile[k][cc + 2] = v[2]; tile[k][cc + 3] = v[3];
    }
  }
  __syncthreads();
  const int c = t >> 2;
  const int kc = (t & 3) << 4;
  #pragma unroll
  for (int h = 0; h < 2; ++h) {
    int kk = kc + h * 8;
    FragU p;
    if (k0 + kk < K) {
      #pragma unroll
      for (int j = 0; j < 8; ++j) p.h[j] = (__bf16)tile[kk + j][c];
    } else {
      p.s = (short8){0,0,0,0,0,0,0,0};
    }
    *(short8*)(out + (size_t)c * Kpad + k0 + kk) = p.s;
  }
}

// ---------------------------------------------------------------------------
// out[i][c] = LeakyReLU( (sum_s P[s][i][:] + self[i][:]) . W[c][:] + 2*b[c] )
// ---------------------------------------------------------------------------
__global__ __launch_bounds__(256) void layer_reduce(
    const float* __restrict__ P, int S,
    const float* __restrict__ self, const float* __restrict__ W,
    const float* __restrict__ b, float* __restrict__ out, int M)
{
  __shared__ float xs[4][64];
  const int t = threadIdx.x;
  const int c = t & 63;
  const int grp = t >> 6;
  const int row = blockIdx.x * 4 + grp;
  if (row < M) {
    float x = self[(size_t)row * 64 + c];
    for (int s = 0; s < S; ++s)
      x += P[(size_t)s * M * 64 + (size_t)row * 64 + c];
    xs[grp][c] = x;
  }
  __syncthreads();
  if (row >= M) return;
  float acc = 0.f;
  const f32x4* Wc = (const f32x4*)(W + c * 64);
  #pragma unroll
  for (int k4 = 0; k4 < 16; ++k4) {
    f32x4 wv = Wc[k4];
    acc += xs[grp][k4 * 4 + 0] * wv[0] + xs[grp][k4 * 4 + 1] * wv[1]
         + xs[grp][k4 * 4 + 2] * wv[2] + xs[grp][k4 * 4 + 3] * wv[3];
  }
  float v = acc + 2.0f * b[c];
  out[(size_t)row * 64 + c] = (v > 0.f) ? v : 0.01f * v;
}

// ---------------------------------------------------------------------------
__global__ __launch_bounds__(256) void gather_score(
    const int* __restrict__ uid, const int* __restrict__ mid,
    const float* __restrict__ u0, const float* __restrict__ u1,
    const float* __restrict__ u2, const float* __restrict__ u3,
    const float* __restrict__ m0, const float* __restrict__ m1,
    const float* __restrict__ m2, const float* __restrict__ m3,
    const float* __restrict__ oW, const float* __restrict__ ob,
    float* __restrict__ scores, int B)
{
  const int wave = threadIdx.x >> 6;
  const int lane = threadIdx.x & 63;
  const int b = blockIdx.x * 4 + wave;
  if (b >= B) return;
  const size_t ub = (size_t)uid[b] * 64 + lane;
  const size_t mb = (size_t)mid[b] * 64 + lane;
  float acc = u0[ub] * m0[mb] * oW[lane]
            + u1[ub] * m1[mb] * oW[64 + lane]
            + u2[ub] * m2[mb] * oW[128 + lane]
            + u3[ub] * m3[mb] * oW[192 + lane];
  #pragma unroll
  for (int off = 32; off > 0; off >>= 1)
    acc += __shfl_down(acc, off, 64);
  if (lane == 0) scores[b] = acc + ob[0];
}

// ---------------------------------------------------------------------------
extern "C" void kernel_launch(void* const* d_in, const int* in_sizes, int n_in,
                              void* d_out, int out_size, void* d_ws, size_t ws_size,
                              hipStream_t stream)
{
  const float* user_adj  = (const float*)d_in[0];
  const float* movie_adj = (const float*)d_in[1];
  const int*   user_id   = (const int*)d_in[2];
  const int*   movie_id  = (const int*)d_in[3];
  const float* user_emb  = (const float*)d_in[4];
  const float* movie_emb = (const float*)d_in[5];
  const float* user_Ws   = (const float*)d_in[6];
  const float* user_bs   = (const float*)d_in[7];
  const float* movie_Ws  = (const float*)d_in[8];
  const float* movie_bs  = (const float*)d_in[9];
  const float* out_W     = (const float*)d_in[10];
  const float* out_b     = (const float*)d_in[11];

  const int NU = 20000, NM = 10000, E = 64, B = 8192;
  const int rbU = 157, rbM = 79;          // ceil(M/128)
  const int KT_U = 157, KT_M = 313;       // ceil(K/64)
  const int NMpad = KT_U * 64;            // 10048
  const int NUpad = KT_M * 64;            // 20032
  const int SU = 5, SM = 10;              // k-splits (64 32-k steps each)

  char* ws = (char*)d_ws;
  size_t o = 0;
  __bf16* Au_c = (__bf16*)(ws + o); o += (size_t)rbU * KT_U * 16384;  // 403.8 MB
  __bf16* Am_c = (__bf16*)(ws + o); o += (size_t)rbM * KT_M * 16384;  // 405.1 MB
  float*  uP   = (float*)(ws + o);  o += (size_t)SU * NU * 64 * 4;
  float*  mP   = (float*)(ws + o);  o += (size_t)SM * NM * 64 * 4;
  float*  u1   = (float*)(ws + o);  o += (size_t)NU * 64 * 4;
  float*  u2   = (float*)(ws + o);  o += (size_t)NU * 64 * 4;
  float*  m1   = (float*)(ws + o);  o += (size_t)NM * 64 * 4;
  float*  m2   = (float*)(ws + o);  o += (size_t)NM * 64 * 4;
  __bf16* uT   = (__bf16*)(ws + o); o += (size_t)64 * NUpad * 2;
  __bf16* mT   = (__bf16*)(ws + o); o += (size_t)64 * NMpad * 2;

  float* scores = (float*)d_out;
  float* u3 = scores + B;
  float* m3 = u3 + (size_t)NU * E;

  const int nbU = rbU * SU;   // 785
  const int nbM = rbM * SM;   // 790

  const float* uCur = user_emb;
  const float* mCur = movie_emb;
  for (int l = 0; l < 3; ++l) {
    float* uNext = (l == 0) ? u1 : (l == 1) ? u2 : u3;
    float* mNext = (l == 0) ? m1 : (l == 1) ? m2 : m3;

    transpose_cvt<<<NMpad / 64, 256, 0, stream>>>(mCur, mT, NM, NMpad);
    transpose_cvt<<<NUpad / 64, 256, 0, stream>>>(uCur, uT, NU, NUpad);

    if (l == 0) {
      gemm_l0<<<nbU + nbM, 256, 0, stream>>>(
          user_adj, mT, Au_c, uP, NU, NM, KT_U, NMpad,
          movie_adj, uT, Am_c, mP, NM, NU, KT_M, NUpad,
          nbU, rbU, rbM);
    } else {
      gemm_l12<<<nbU + nbM, 256, 0, stream>>>(
          Au_c, mT, uP, NU, KT_U, NMpad,
          Am_c, uT, mP, NM, KT_M, NUpad,
          nbU, rbU, rbM);
    }

    layer_reduce<<<(NU + 3) / 4, 256, 0, stream>>>(
        uP, SU, uCur, user_Ws + (size_t)l * E * E, user_bs + (size_t)l * E, uNext, NU);
    layer_reduce<<<(NM + 3) / 4, 256, 0, stream>>>(
        mP, SM, mCur, movie_Ws + (size_t)l * E * E, movie_bs + (size_t)l * E, mNext, NM);
    uCur = uNext; mCur = mNext;
  }
  gather_score<<<(B + 3) / 4, 256, 0, stream>>>(
      user_id, movie_id, user_emb, u1, u2, u3,
      movie_emb, m1, m2, m3, out_W, out_b, scores, B);
}